// Round 1
// baseline (159.200 us; speedup 1.0000x reference)
//
#include <hip/hip_runtime.h>
#include <math.h>

// CellList dense masked-distance map, N=6144, no PBC.
// out[i*N+j] = |r_i - r_j| if (i>j && species_i!=-1 && species_j!=-1 &&
//                              dist<=cutoff && sq>0) else 0.
// HBM-write-bound: 151 MB output per launch; floor ~24 us @ 6.3 TB/s.

constexpr int N_ATOMS = 6144;

__global__ __launch_bounds__(256) void cell_list_kernel(
    const float* __restrict__ coords,   // [N][3] f32
    const int*   __restrict__ species,  // [N] i32
    const int*   __restrict__ cutoff_p, // [1] i32
    float*       __restrict__ out)      // [N][N] f32
{
    const int i  = blockIdx.y;                                   // row (uniform per block)
    const int t  = blockIdx.x * blockDim.x + threadIdx.x;        // which float4 of the row
    const int j0 = t * 4;                                        // first of 4 columns

    const float cutoff = (float)cutoff_p[0];

    // Row-i data: blockIdx-uniform -> compiler emits scalar loads.
    const float xi = coords[3 * i + 0];
    const float yi = coords[3 * i + 1];
    const float zi = coords[3 * i + 2];
    const int   si = species[i];

    // 4 consecutive j atoms = 12 consecutive floats = 3 aligned float4 loads
    // (j0 is a multiple of 4 -> byte offset 48*t, 16B-aligned).
    const float4* cj = reinterpret_cast<const float4*>(coords + 3 * (size_t)j0);
    const float4 c0 = cj[0];
    const float4 c1 = cj[1];
    const float4 c2 = cj[2];
    const int4 sjv = *reinterpret_cast<const int4*>(species + j0);

    const float xj[4] = {c0.x, c0.w, c1.z, c2.y};
    const float yj[4] = {c0.y, c1.x, c1.w, c2.z};
    const float zj[4] = {c0.z, c1.y, c2.x, c2.w};
    const int   sj[4] = {sjv.x, sjv.y, sjv.z, sjv.w};

    float4 res;
    float* r = &res.x;
#pragma unroll
    for (int k = 0; k < 4; ++k) {
        const int j = j0 + k;
        // Exact numpy evaluation order: (dx*dx + dy*dy) + dz*dz, no FMA
        // contraction -- keeps the dist<=cutoff mask bit-exact vs the ref.
        const float dx = __fsub_rn(xi, xj[k]);
        const float dy = __fsub_rn(yi, yj[k]);
        const float dz = __fsub_rn(zi, zj[k]);
        const float sq = __fadd_rn(__fadd_rn(__fmul_rn(dx, dx), __fmul_rn(dy, dy)),
                                   __fmul_rn(dz, dz));
        const float dist = sqrtf(sq > 0.0f ? sq : 1.0f);  // safe sqrt (diag sq==0)
        const bool m = (i > j) && (si != -1) && (sj[k] != -1) &&
                       (dist <= cutoff) && (sq > 0.0f);
        r[k] = m ? dist : 0.0f;
    }

    // Coalesced float4 store: consecutive lanes -> consecutive 16B chunks.
    reinterpret_cast<float4*>(out + (size_t)i * N_ATOMS)[t] = res;
}

extern "C" void kernel_launch(void* const* d_in, const int* in_sizes, int n_in,
                              void* d_out, int out_size, void* d_ws, size_t ws_size,
                              hipStream_t stream) {
    // setup_inputs() order: species (i32 [1,N]), coordinates (f32 [1,N,3]),
    // cutoff (python int -> i32 [1]).
    const int*   species = (const int*)d_in[0];
    const float* coords  = (const float*)d_in[1];
    const int*   cutoff  = (const int*)d_in[2];
    float*       out     = (float*)d_out;

    dim3 block(256);
    dim3 grid(N_ATOMS / 4 / 256, N_ATOMS);  // (6, 6144): 4 cols/thread, 1 row/block-row
    hipLaunchKernelGGL(cell_list_kernel, grid, block, 0, stream,
                       coords, species, cutoff, out);
}